// Round 8
// baseline (263.128 us; speedup 1.0000x reference)
//
#include <hip/hip_runtime.h>
#include <hip/hip_bf16.h>

// LVQ: out[n] = classes[argmin_k ||x_n - c_k||^2]
// N=65536, D=512, K=1024, classes int32.
//
// score[n][k] = csq[k] - 2 * x_n . c_k   (x_sq dropped: row-constant)
// cross via 3-pass bf16-split MFMA (xh*ch + xh*cl + xl*ch), fp32 accum.
// Round 8: 128x128 tile, BK=32, 4 waves (2x2, 64x64 wave tile), 64 KB dbuf
// -> 2 blocks/CU: independent barrier domains give cross-block overlap
// (m97 regime) ON TOP of r6's counted-vmcnt schedule (top vmcnt(2),
// mid vmcnt(6), never 0 mid-loop; 2 barriers/tile).

#define N_ROWS 65536
#define DIM    512
#define K_CB   1024
#define NT     16          // DIM / BK, BK=32
#define LDSBUF 16384       // elements per buffer: Ah|Al|Bh|Bl = 4 x 4096

typedef short bf16x8 __attribute__((ext_vector_type(8)));
typedef float f32x4  __attribute__((ext_vector_type(4)));

__device__ __forceinline__ unsigned short f2bf_rn(float f) {
    unsigned u = __float_as_uint(f);
    unsigned r = (u + 0x7FFFu + ((u >> 16) & 1u)) >> 16;
    return (unsigned short)r;
}
__device__ __forceinline__ float bf2f(unsigned short h) {
    return __uint_as_float(((unsigned)h) << 16);
}

__device__ __forceinline__ void gload16(const void* g, void* l) {
    __builtin_amdgcn_global_load_lds(
        (const __attribute__((address_space(1))) unsigned int*)g,
        (__attribute__((address_space(3))) unsigned int*)l, 16, 0, 0);
}

// ---------------- init: packed per-row (min,argmin) to +inf ----------------
__global__ void init_kernel(unsigned long long* __restrict__ packed) {
    int n = blockIdx.x * 256 + threadIdx.x;
    if (n < N_ROWS) packed[n] = ~0ull;
}

// ---------------- csq[k] = sum_d C[k][d]^2 (fp32) ----------------
__global__ void csq_kernel(const float* __restrict__ C, float* __restrict__ csq) {
    int wid  = (blockIdx.x * blockDim.x + threadIdx.x) >> 6;   // one wave per k
    int lane = threadIdx.x & 63;
    const float4* p = (const float4*)(C + (size_t)wid * DIM);
    float4 a = p[lane * 2];
    float4 b = p[lane * 2 + 1];
    float s = a.x*a.x + a.y*a.y + a.z*a.z + a.w*a.w
            + b.x*b.x + b.y*b.y + b.z*b.z + b.w*b.w;
    #pragma unroll
    for (int m = 1; m < 64; m <<= 1) s += __shfl_xor(s, m, 64);
    if (lane == 0) csq[wid] = s;
}

// ---------------- one-shot fp32 -> bf16 hi/lo split ----------------
__global__ void split_kernel(const float* __restrict__ src,
                             unsigned short* __restrict__ h,
                             unsigned short* __restrict__ l, int n4) {
    int stride = gridDim.x * 256;
    for (int i = blockIdx.x * 256 + threadIdx.x; i < n4; i += stride) {
        float4 v = ((const float4*)src)[i];
        ushort4 hh, ll;
        float f;
        f = v.x; hh.x = f2bf_rn(f); ll.x = f2bf_rn(f - bf2f(hh.x));
        f = v.y; hh.y = f2bf_rn(f); ll.y = f2bf_rn(f - bf2f(hh.y));
        f = v.z; hh.z = f2bf_rn(f); ll.z = f2bf_rn(f - bf2f(hh.z));
        f = v.w; hh.w = f2bf_rn(f); ll.w = f2bf_rn(f - bf2f(hh.w));
        ((ushort4*)h)[i] = hh;
        ((ushort4*)l)[i] = ll;
    }
}

// ---------------- fused GEMM + argmin, 2-blocks/CU counted pipeline --------
// LDS per buffer (elements): Ah[0,4096) Al[4096,8192) Bh[8192,12288)
// Bl[12288,16384); each array [row][group 0..3][8 elems]. LDS[row][g] holds
// GLOBAL k-group g ^ ((row>>1)&3) (swizzle on the per-lane global source;
// linear LDS dest as global_load_lds requires). Fragment reads use the same
// XOR (0 conflicts, verified r2-r4/r6).
// Per-thread gloads per tile (8): h1 = [AhA1, AlA1, ChB0, ChB1, ClB0, ClB1]
// (A rows {0-31,64-95} + all B), h2 = [AhA2, AlA2] (A rows {32-63,96-127}).
__global__ __launch_bounds__(256, 2)
void gemm_argmin(const unsigned short* __restrict__ Xh,
                 const unsigned short* __restrict__ Xl,
                 const unsigned short* __restrict__ Ch,
                 const unsigned short* __restrict__ Cl,
                 const float* __restrict__ csq,
                 unsigned long long* __restrict__ packed) {
    extern __shared__ unsigned short smem[];   // 2 * LDSBUF elements (64 KB)

    // XCD-aware mapping: the 8 col-tiles of one row-tile run on one XCD
    // -> X row-tile (256 KB of Xh+Xl) L2-resident across them.
    int b  = blockIdx.x;
    int x  = b & 7;
    int m8 = b >> 3;                   // 0..511
    int rowtile = x * 64 + (m8 >> 3);  // 0..511
    int coltile = m8 & 7;              // 0..7
    int n0 = rowtile * 128;
    int k0 = coltile * 128;

    int tid  = threadIdx.x;
    int w    = tid >> 6;
    int lane = tid & 63;
    int wr   = w >> 1, wc = w & 1;     // 2M x 2N waves; wave tile 64x64
    int rbase = wr * 64, cbase = wc * 64;
    int lrow = lane & 15;
    int lk   = lane >> 4;              // 0..3
    int sg   = lk ^ ((lrow >> 1) & 3); // swizzled k-group for frag reads

    // staging invariants: thread -> (srow = tid>>2, sgrp = tid&3)
    int srow = tid >> 2;               // 0..63
    int sgrp = tid & 3;
    int r1   = (srow < 32) ? srow : srow + 32;     // A-h1 row {0-31,64-95}
    int ggA  = sgrp ^ ((r1 >> 1) & 3);             // same for r1 and r1+32
    int gB   = sgrp ^ ((srow >> 1) & 3);           // same for srow and srow+64
    size_t oA1 = (size_t)(n0 + r1) * DIM + ggA * 8;
    size_t oA2 = oA1 + (size_t)32 * DIM;
    size_t oB0 = (size_t)(k0 + srow) * DIM + gB * 8;
    size_t oB1 = oB0 + (size_t)64 * DIM;
    // wave-uniform LDS dest offsets (HW adds lane*16B = lane*8 elems)
    int dA1  = (w >> 1) * 2048 + (w & 1) * 512;   // rows {0,16,64,80}+..
    int dA2  = dA1 + 1024;                        // +32 rows
    int dB0  = 8192 + w * 512;                    // B rows w*16..
    int dB1  = dB0 + 2048;                        // +64 rows
    int dBl0 = dB0 + 4096;
    int dBl1 = dB1 + 4096;

    f32x4 acc[4][4];
    #pragma unroll
    for (int i = 0; i < 4; i++)
        #pragma unroll
        for (int j = 0; j < 4; j++)
            acc[i][j] = (f32x4){0.f, 0.f, 0.f, 0.f};

    bf16x8 bh[4], bl[4], ah[2], al[2];

    auto mfma_half = [&](int mb) {
        __builtin_amdgcn_s_setprio(1);
        // pass-major: 8 independent MFMAs between dependent acc reuses
        #pragma unroll
        for (int mm = 0; mm < 2; mm++)
            #pragma unroll
            for (int n = 0; n < 4; n++)
                acc[mb + mm][n] = __builtin_amdgcn_mfma_f32_16x16x32_bf16(ah[mm], bh[n], acc[mb + mm][n], 0, 0, 0);
        #pragma unroll
        for (int mm = 0; mm < 2; mm++)
            #pragma unroll
            for (int n = 0; n < 4; n++)
                acc[mb + mm][n] = __builtin_amdgcn_mfma_f32_16x16x32_bf16(ah[mm], bl[n], acc[mb + mm][n], 0, 0, 0);
        #pragma unroll
        for (int mm = 0; mm < 2; mm++)
            #pragma unroll
            for (int n = 0; n < 4; n++)
                acc[mb + mm][n] = __builtin_amdgcn_mfma_f32_16x16x32_bf16(al[mm], bh[n], acc[mb + mm][n], 0, 0, 0);
        __builtin_amdgcn_s_setprio(0);
    };

    // prologue: tile 0, canonical issue order (h1 first 6, h2 last 2)
    {
        unsigned short* b0 = smem;
        gload16(Xh + oA1, b0 + dA1);
        gload16(Xl + oA1, b0 + 4096 + dA1);
        gload16(Ch + oB0, b0 + dB0);
        gload16(Ch + oB1, b0 + dB1);
        gload16(Cl + oB0, b0 + dBl0);
        gload16(Cl + oB1, b0 + dBl1);
        gload16(Xh + oA2, b0 + dA2);
        gload16(Xl + oA2, b0 + 4096 + dA2);
    }

    for (int t = 0; t < NT; ++t) {
        // top: h1(t) done (oldest 6); h2(t) may still fly
        asm volatile("s_waitcnt vmcnt(2)" ::: "memory");
        __builtin_amdgcn_s_barrier();
        asm volatile("" ::: "memory");

        const unsigned short* buf = smem + (t & 1) * LDSBUF;
        const unsigned short* pA = buf + (rbase + lrow) * 32 + sg * 8;
        const unsigned short* pB = buf + 8192 + (cbase + lrow) * 32 + sg * 8;
        unsigned short* nbuf = smem + ((t + 1) & 1) * LDSBUF;
        size_t dnx = (size_t)(t + 1) * 32;
        bool pre = (t + 1 < NT);

        // ---- half 1: B frags (whole tile) + A m0,m1; issue h1(t+1) ----
        #pragma unroll
        for (int n = 0; n < 4; n++) {
            bh[n] = *(const bf16x8*)(pB + n * 512);
            bl[n] = *(const bf16x8*)(pB + 4096 + n * 512);
        }
        ah[0] = *(const bf16x8*)(pA);
        ah[1] = *(const bf16x8*)(pA + 512);
        al[0] = *(const bf16x8*)(pA + 4096);
        al[1] = *(const bf16x8*)(pA + 4096 + 512);
        if (pre) {
            gload16(Xh + oA1 + dnx, nbuf + dA1);
            gload16(Xl + oA1 + dnx, nbuf + 4096 + dA1);
            gload16(Ch + oB0 + dnx, nbuf + dB0);
            gload16(Ch + oB1 + dnx, nbuf + dB1);
            gload16(Cl + oB0 + dnx, nbuf + dBl0);
            gload16(Cl + oB1 + dnx, nbuf + dBl1);
        }
        mfma_half(0);

        // mid: h2(t) done (oldest 2); h1(t+1)'s 6 stay in flight
        if (pre) asm volatile("s_waitcnt vmcnt(6)" ::: "memory");
        else     asm volatile("s_waitcnt vmcnt(0)" ::: "memory");
        __builtin_amdgcn_s_barrier();
        asm volatile("" ::: "memory");

        // ---- half 2: A m2,m3; issue h2(t+1) ----
        ah[0] = *(const bf16x8*)(pA + 2 * 512);
        ah[1] = *(const bf16x8*)(pA + 3 * 512);
        al[0] = *(const bf16x8*)(pA + 4096 + 2 * 512);
        al[1] = *(const bf16x8*)(pA + 4096 + 3 * 512);
        if (pre) {
            gload16(Xh + oA2 + dnx, nbuf + dA2);
            gload16(Xl + oA2 + dnx, nbuf + 4096 + dA2);
        }
        mfma_half(2);
        // tile boundary: next top barrier (vmcnt(2)) protects buf reuse --
        // all waves' half-2 ds_reads drained (lgkmcnt before MFMA) by then.
    }

    // Epilogue: score = csq[col] - 2*cross; per-row packed-min, atomic merge.
    float cs[4];
    #pragma unroll
    for (int n = 0; n < 4; n++) cs[n] = csq[k0 + cbase + n * 16 + lrow];

    #pragma unroll
    for (int m = 0; m < 4; m++) {
        #pragma unroll
        for (int r = 0; r < 4; r++) {
            unsigned long long best = ~0ull;
            #pragma unroll
            for (int n = 0; n < 4; n++) {
                float s = cs[n] - 2.0f * acc[m][n][r];
                unsigned kb  = __float_as_uint(s);
                unsigned key = kb ^ (unsigned)(((int)kb >> 31) | 0x80000000);
                unsigned col = (unsigned)(k0 + cbase + n * 16 + lrow);
                unsigned long long pk = (((unsigned long long)key) << 32) | col;
                best = pk < best ? pk : best;
            }
            #pragma unroll
            for (int mask = 1; mask <= 8; mask <<= 1) {
                unsigned hi = __shfl_xor((unsigned)(best >> 32), mask, 64);
                unsigned lo = __shfl_xor((unsigned)(best & 0xFFFFFFFFu), mask, 64);
                unsigned long long other = (((unsigned long long)hi) << 32) | lo;
                best = other < best ? other : best;
            }
            if (lrow == 0) {
                int grow = n0 + rbase + m * 16 + lk * 4 + r;
                atomicMin(&packed[grow], best);
            }
        }
    }
}

// ---------------- fallback GEMM (in-kernel conversion, round-1 path) -------
__device__ __forceinline__ void stage_tile_fb(const float* __restrict__ src,
                                              unsigned short* __restrict__ Hh,
                                              unsigned short* __restrict__ Hl,
                                              int t) {
    int rsub = t >> 4;
    int f4i  = t & 15;
    int g    = f4i >> 1;
    int off  = (f4i & 1) * 4;
    #pragma unroll
    for (int p = 0; p < 8; p++) {
        int row = p * 16 + rsub;
        float4 v = *(const float4*)(src + (size_t)row * DIM + f4i * 4);
        ushort4 h, l;
        float f;
        f = v.x; h.x = f2bf_rn(f); l.x = f2bf_rn(f - bf2f(h.x));
        f = v.y; h.y = f2bf_rn(f); l.y = f2bf_rn(f - bf2f(h.y));
        f = v.z; h.z = f2bf_rn(f); l.z = f2bf_rn(f - bf2f(h.z));
        f = v.w; h.w = f2bf_rn(f); l.w = f2bf_rn(f - bf2f(h.w));
        int sg  = g ^ (row & 7);
        int idx = row * 64 + sg * 8 + off;
        *(ushort4*)(Hh + idx) = h;
        *(ushort4*)(Hl + idx) = l;
    }
}

__global__ __launch_bounds__(256, 2)
void gemm_argmin_fb(const float* __restrict__ X, const float* __restrict__ C,
                    const float* __restrict__ csq,
                    unsigned long long* __restrict__ packed) {
    __shared__ unsigned short AhL[128 * 64];
    __shared__ unsigned short AlL[128 * 64];
    __shared__ unsigned short BhL[128 * 64];
    __shared__ unsigned short BlL[128 * 64];

    int b = blockIdx.x;
    int x = b & 7;
    int m8 = b >> 3;
    int rowtile = x * 64 + (m8 >> 3);
    int coltile = m8 & 7;
    int n0 = rowtile * 128;
    int k0 = coltile * 128;

    int t    = threadIdx.x;
    int w    = t >> 6;
    int lane = t & 63;
    int wr   = w >> 1, wc = w & 1;
    int rbase = wr * 64, cbase = wc * 64;
    int lrow = lane & 15;
    int lk   = lane >> 4;

    f32x4 acc[4][4];
    #pragma unroll
    for (int i = 0; i < 4; i++)
        #pragma unroll
        for (int j = 0; j < 4; j++)
            acc[i][j] = (f32x4){0.f, 0.f, 0.f, 0.f};

    for (int d0 = 0; d0 < DIM; d0 += 64) {
        stage_tile_fb(X + (size_t)n0 * DIM + d0, AhL, AlL, t);
        stage_tile_fb(C + (size_t)k0 * DIM + d0, BhL, BlL, t);
        __syncthreads();

        #pragma unroll
        for (int kk = 0; kk < 2; kk++) {
            int gidx = kk * 4 + lk;
            bf16x8 ah[4], al[4], bh[4], bl[4];
            #pragma unroll
            for (int m = 0; m < 4; m++) {
                int row = rbase + m * 16 + lrow;
                int sg  = gidx ^ (row & 7);
                ah[m] = *(const bf16x8*)&AhL[row * 64 + sg * 8];
                al[m] = *(const bf16x8*)&AlL[row * 64 + sg * 8];
            }
            #pragma unroll
            for (int n = 0; n < 4; n++) {
                int col = cbase + n * 16 + lrow;
                int sg  = gidx ^ (col & 7);
                bh[n] = *(const bf16x8*)&BhL[col * 64 + sg * 8];
                bl[n] = *(const bf16x8*)&BlL[col * 64 + sg * 8];
            }
            #pragma unroll
            for (int m = 0; m < 4; m++)
                #pragma unroll
                for (int n = 0; n < 4; n++) {
                    acc[m][n] = __builtin_amdgcn_mfma_f32_16x16x32_bf16(ah[m], bh[n], acc[m][n], 0, 0, 0);
                    acc[m][n] = __builtin_amdgcn_mfma_f32_16x16x32_bf16(ah[m], bl[n], acc[m][n], 0, 0, 0);
                    acc[m][n] = __builtin_amdgcn_mfma_f32_16x16x32_bf16(al[m], bh[n], acc[m][n], 0, 0, 0);
                }
        }
        __syncthreads();
    }

    float cs[4];
    #pragma unroll
    for (int n = 0; n < 4; n++) cs[n] = csq[k0 + cbase + n * 16 + lrow];

    #pragma unroll
    for (int m = 0; m < 4; m++) {
        #pragma unroll
        for (int r = 0; r < 4; r++) {
            unsigned long long best = ~0ull;
            #pragma unroll
            for (int n = 0; n < 4; n++) {
                float s = cs[n] - 2.0f * acc[m][n][r];
                unsigned kb  = __float_as_uint(s);
                unsigned key = kb ^ (unsigned)(((int)kb >> 31) | 0x80000000);
                unsigned col = (unsigned)(k0 + cbase + n * 16 + lrow);
                unsigned long long pk = (((unsigned long long)key) << 32) | col;
                best = pk < best ? pk : best;
            }
            #pragma unroll
            for (int mask = 1; mask <= 8; mask <<= 1) {
                unsigned hi = __shfl_xor((unsigned)(best >> 32), mask, 64);
                unsigned lo = __shfl_xor((unsigned)(best & 0xFFFFFFFFu), mask, 64);
                unsigned long long other = (((unsigned long long)hi) << 32) | lo;
                best = other < best ? other : best;
            }
            if (lrow == 0) {
                int grow = n0 + rbase + m * 16 + lk * 4 + r;
                atomicMin(&packed[grow], best);
            }
        }
    }
}

// ---------------- winner -> class ----------------
__global__ void map_kernel(const unsigned long long* __restrict__ packed,
                           const int* __restrict__ classes,
                           int* __restrict__ out) {
    int n = blockIdx.x * 256 + threadIdx.x;
    if (n < N_ROWS) {
        unsigned col = (unsigned)(packed[n] & 0xFFFFFFFFull);
        out[n] = classes[col];
    }
}

extern "C" void kernel_launch(void* const* d_in, const int* in_sizes, int n_in,
                              void* d_out, int out_size, void* d_ws, size_t ws_size,
                              hipStream_t stream) {
    const float* X       = (const float*)d_in[0];
    const float* C       = (const float*)d_in[1];
    const int*   classes = (const int*)d_in[2];
    int*         out     = (int*)d_out;

    char* ws = (char*)d_ws;
    size_t off = 0;
    unsigned long long* packed = (unsigned long long*)(ws + off); off += (size_t)N_ROWS * 8;
    float* csq = (float*)(ws + off);                              off += (size_t)K_CB * 4;
    unsigned short* Xh = (unsigned short*)(ws + off);             off += (size_t)N_ROWS * DIM * 2;
    unsigned short* Xl = (unsigned short*)(ws + off);             off += (size_t)N_ROWS * DIM * 2;
    unsigned short* Ch = (unsigned short*)(ws + off);             off += (size_t)K_CB * DIM * 2;
    unsigned short* Cl = (unsigned short*)(ws + off);             off += (size_t)K_CB * DIM * 2;

    init_kernel<<<N_ROWS / 256, 256, 0, stream>>>(packed);
    csq_kernel<<<K_CB / 4, 256, 0, stream>>>(C, csq);

    if (ws_size >= off) {
        split_kernel<<<2048, 256, 0, stream>>>(X, Xh, Xl, N_ROWS * DIM / 4);
        split_kernel<<<512, 256, 0, stream>>>(C, Ch, Cl, K_CB * DIM / 4);
        hipFuncSetAttribute((const void*)gemm_argmin,
                            hipFuncAttributeMaxDynamicSharedMemorySize,
                            2 * LDSBUF * sizeof(unsigned short));
        gemm_argmin<<<(N_ROWS / 128) * (K_CB / 128), 256,
                      2 * LDSBUF * sizeof(unsigned short), stream>>>(
            Xh, Xl, Ch, Cl, csq, packed);
    } else {
        gemm_argmin_fb<<<(N_ROWS / 128) * (K_CB / 128), 256, 0, stream>>>(X, C, csq, packed);
    }
    map_kernel<<<N_ROWS / 256, 256, 0, stream>>>(packed, classes, out);
}

// Round 9
// 253.761 us; speedup vs baseline: 1.0369x; 1.0369x over previous
//
#include <hip/hip_runtime.h>
#include <hip/hip_bf16.h>

// LVQ: out[n] = classes[argmin_k ||x_n - c_k||^2]
// N=65536, D=512, K=1024, classes int32.
//
// score[n][k] = csq[k] - 2 * x_n . c_k   (x_sq dropped: row-constant)
// cross via 3-pass bf16-split MFMA (xh*ch + xh*cl + xl*ch), fp32 accum.
// Round 9: ONE barrier + ONE region per K-tile. All 8 of tile t+1's gloads
// issued in one early bundle during tile t, so top-of-tile vmcnt(0) is a
// free drain (loads landed ~1 tile ago). No mid barrier -> 24 ds_reads,
// 8 gload issues and 96 MFMAs live in one scheduling region; compiler's
// fine lgkmcnt interleave overlaps LDS reads under MFMA (the 2-barrier
// structure forbade this; r6 measured MFMA+LDS serialized: 7425 cyc/tile
// vs 3725 MFMA floor).

#define N_ROWS 65536
#define DIM    512
#define K_CB   1024
#define NT     16          // DIM / BK, BK=32
#define LDSBUF 32768       // elements per buffer: Ah|Al|Bh|Bl = 4 x 8192

typedef short bf16x8 __attribute__((ext_vector_type(8)));
typedef float f32x4  __attribute__((ext_vector_type(4)));

__device__ __forceinline__ unsigned short f2bf_rn(float f) {
    unsigned u = __float_as_uint(f);
    unsigned r = (u + 0x7FFFu + ((u >> 16) & 1u)) >> 16;
    return (unsigned short)r;
}
__device__ __forceinline__ float bf2f(unsigned short h) {
    return __uint_as_float(((unsigned)h) << 16);
}

__device__ __forceinline__ void gload16(const void* g, void* l) {
    __builtin_amdgcn_global_load_lds(
        (const __attribute__((address_space(1))) unsigned int*)g,
        (__attribute__((address_space(3))) unsigned int*)l, 16, 0, 0);
}

// ---------------- init: packed per-row (min,argmin) to +inf ----------------
__global__ void init_kernel(unsigned long long* __restrict__ packed) {
    int n = blockIdx.x * 256 + threadIdx.x;
    if (n < N_ROWS) packed[n] = ~0ull;
}

// ---------------- csq[k] = sum_d C[k][d]^2 (fp32) ----------------
__global__ void csq_kernel(const float* __restrict__ C, float* __restrict__ csq) {
    int wid  = (blockIdx.x * blockDim.x + threadIdx.x) >> 6;   // one wave per k
    int lane = threadIdx.x & 63;
    const float4* p = (const float4*)(C + (size_t)wid * DIM);
    float4 a = p[lane * 2];
    float4 b = p[lane * 2 + 1];
    float s = a.x*a.x + a.y*a.y + a.z*a.z + a.w*a.w
            + b.x*b.x + b.y*b.y + b.z*b.z + b.w*b.w;
    #pragma unroll
    for (int m = 1; m < 64; m <<= 1) s += __shfl_xor(s, m, 64);
    if (lane == 0) csq[wid] = s;
}

// ---------------- one-shot fp32 -> bf16 hi/lo split ----------------
__global__ void split_kernel(const float* __restrict__ src,
                             unsigned short* __restrict__ h,
                             unsigned short* __restrict__ l, int n4) {
    int stride = gridDim.x * 256;
    for (int i = blockIdx.x * 256 + threadIdx.x; i < n4; i += stride) {
        float4 v = ((const float4*)src)[i];
        ushort4 hh, ll;
        float f;
        f = v.x; hh.x = f2bf_rn(f); ll.x = f2bf_rn(f - bf2f(hh.x));
        f = v.y; hh.y = f2bf_rn(f); ll.y = f2bf_rn(f - bf2f(hh.y));
        f = v.z; hh.z = f2bf_rn(f); ll.z = f2bf_rn(f - bf2f(hh.z));
        f = v.w; hh.w = f2bf_rn(f); ll.w = f2bf_rn(f - bf2f(hh.w));
        ((ushort4*)h)[i] = hh;
        ((ushort4*)l)[i] = ll;
    }
}

// ---------------- fused GEMM + argmin, 1-barrier/tile pipeline -------------
// LDS per buffer: Ah[0,8192) Al[8192,16384) Bh[16384,24576) Bl[24576,32768),
// each array [row][group 0..3][8 elems]; LDS[row][g] holds GLOBAL k-group
// g ^ ((row>>1)&3) (swizzle on the per-lane global source address; linear
// LDS dest as global_load_lds requires). Fragment reads use the same XOR
// (verified 0 conflicts, r2-r8).
__global__ __launch_bounds__(512, 2)
void gemm_argmin(const unsigned short* __restrict__ Xh,
                 const unsigned short* __restrict__ Xl,
                 const unsigned short* __restrict__ Ch,
                 const unsigned short* __restrict__ Cl,
                 const float* __restrict__ csq,
                 unsigned long long* __restrict__ packed) {
    extern __shared__ unsigned short smem[];   // 2 * LDSBUF elements (128 KB)

    // XCD-aware mapping: the 4 col-tiles of one row-tile run concurrently
    // on one XCD -> X tile (512 KB) fetched into that L2 once.
    int b  = blockIdx.x;
    int x  = b & 7;
    int m8 = b >> 3;                   // 0..127
    int rowtile = x * 32 + (m8 >> 2);  // 0..255
    int coltile = m8 & 3;              // 0..3
    int n0 = rowtile * 256;
    int k0 = coltile * 256;

    int tid  = threadIdx.x;
    int w    = tid >> 6;
    int lane = tid & 63;
    int wr   = w >> 2, wc = w & 3;     // 2M x 4N waves; wave tile 128x64
    int rbase = wr * 128, cbase = wc * 64;
    int lrow = lane & 15;
    int lk   = lane >> 4;              // 0..3
    int sg   = lk ^ ((lrow >> 1) & 3); // swizzled k-group for frag reads

    // staging invariants: thread -> (srow = tid>>2, sgrp = tid&3)
    int srow = tid >> 2;               // 0..127
    int sgrp = tid & 3;
    int r1   = (srow < 64) ? srow : srow + 64;     // A rows {0-63,128-191}
    int ggA  = sgrp ^ ((r1 >> 1) & 3);             // same for r1 and r1+64
    int gB   = sgrp ^ ((srow >> 1) & 3);           // same for srow and srow+128
    size_t oA1 = (size_t)(n0 + r1) * DIM + ggA * 8;
    size_t oA2 = oA1 + (size_t)64 * DIM;
    size_t oB0 = (size_t)(k0 + srow) * DIM + gB * 8;
    size_t oB1 = oB0 + (size_t)128 * DIM;
    // wave-uniform LDS dest offsets (HW adds lane*16B)
    int rowA1_0 = (w < 4) ? w * 16 : w * 16 + 64;
    int dA1  = rowA1_0 * 32;
    int dA2  = dA1 + 2048;             // +64 rows
    int dB0  = 16384 + w * 512;        // B rows w*16..
    int dB1  = dB0 + 4096;             // +128 rows
    int dBl0 = dB0 + 8192;
    int dBl1 = dB1 + 8192;

    f32x4 acc[8][4];
    #pragma unroll
    for (int i = 0; i < 8; i++)
        #pragma unroll
        for (int j = 0; j < 4; j++)
            acc[i][j] = (f32x4){0.f, 0.f, 0.f, 0.f};

    bf16x8 bh[4], bl[4];

    // issue ALL 8 staging gloads for K-tile t into buf[t&1] (one bundle)
    auto issue_tile = [&](int t) {
        unsigned short* bufn = smem + (t & 1) * LDSBUF;
        size_t d = (size_t)t * 32;
        gload16(Xh + oA1 + d, bufn + dA1);
        gload16(Xl + oA1 + d, bufn + 8192 + dA1);
        gload16(Ch + oB0 + d, bufn + dB0);
        gload16(Ch + oB1 + d, bufn + dB1);
        gload16(Cl + oB0 + d, bufn + dBl0);
        gload16(Cl + oB1 + d, bufn + dBl1);
        gload16(Xh + oA2 + d, bufn + dA2);
        gload16(Xl + oA2 + d, bufn + 8192 + dA2);
    };

    // 48 MFMAs for A-frags mb..mb+3, pass-major (8 independent between
    // dependent accumulator reuses; per-acc order hh, hl, lh as r2-r8).
    auto mfma_half = [&](int mb, const bf16x8* ah, const bf16x8* al) {
        __builtin_amdgcn_s_setprio(1);
        #pragma unroll
        for (int mm = 0; mm < 4; mm++)
            #pragma unroll
            for (int n = 0; n < 4; n++)
                acc[mb + mm][n] = __builtin_amdgcn_mfma_f32_16x16x32_bf16(ah[mm], bh[n], acc[mb + mm][n], 0, 0, 0);
        #pragma unroll
        for (int mm = 0; mm < 4; mm++)
            #pragma unroll
            for (int n = 0; n < 4; n++)
                acc[mb + mm][n] = __builtin_amdgcn_mfma_f32_16x16x32_bf16(ah[mm], bl[n], acc[mb + mm][n], 0, 0, 0);
        #pragma unroll
        for (int mm = 0; mm < 4; mm++)
            #pragma unroll
            for (int n = 0; n < 4; n++)
                acc[mb + mm][n] = __builtin_amdgcn_mfma_f32_16x16x32_bf16(al[mm], bh[n], acc[mb + mm][n], 0, 0, 0);
        __builtin_amdgcn_s_setprio(0);
    };

    issue_tile(0);

    for (int t = 0; t < NT; ++t) {
        // tile t's 8 loads were issued early in tile t-1 (~1 tile of MFMA
        // ago) -> this drain is free; barrier publishes buf[t&1].
        asm volatile("s_waitcnt vmcnt(0)" ::: "memory");
        __builtin_amdgcn_s_barrier();
        asm volatile("" ::: "memory");

        const unsigned short* buf = smem + (t & 1) * LDSBUF;
        const unsigned short* pA = buf + (rbase + lrow) * 32 + sg * 8;
        const unsigned short* pB = buf + 16384 + (cbase + lrow) * 32 + sg * 8;

        // single region: 24 ds_reads + 8 gload issues + 96 MFMAs.
        #pragma unroll
        for (int n = 0; n < 4; n++) {
            bh[n] = *(const bf16x8*)(pB + n * 512);
            bl[n] = *(const bf16x8*)(pB + 8192 + n * 512);
        }
        bf16x8 ah[4], al[4];
        #pragma unroll
        for (int mm = 0; mm < 4; mm++) {
            ah[mm] = *(const bf16x8*)(pA + mm * 512);
            al[mm] = *(const bf16x8*)(pA + 8192 + mm * 512);
        }
        if (t + 1 < NT) issue_tile(t + 1);   // next tile, other buffer

        mfma_half(0, ah, al);

        bf16x8 ah2[4], al2[4];
        #pragma unroll
        for (int mm = 0; mm < 4; mm++) {
            ah2[mm] = *(const bf16x8*)(pA + (4 + mm) * 512);
            al2[mm] = *(const bf16x8*)(pA + 8192 + (4 + mm) * 512);
        }
        mfma_half(4, ah2, al2);
        // next top barrier protects buf reuse: every wave's reads of buf
        // completed (lgkmcnt) before its MFMAs, before it arrives there.
    }

    // Epilogue: score = csq[col] - 2*cross; per-row packed-min, atomic merge.
    float cs[4];
    #pragma unroll
    for (int n = 0; n < 4; n++) cs[n] = csq[k0 + cbase + n * 16 + lrow];

    #pragma unroll
    for (int m = 0; m < 8; m++) {
        #pragma unroll
        for (int r = 0; r < 4; r++) {
            unsigned long long best = ~0ull;
            #pragma unroll
            for (int n = 0; n < 4; n++) {
                float s = cs[n] - 2.0f * acc[m][n][r];
                unsigned kb  = __float_as_uint(s);
                unsigned key = kb ^ (unsigned)(((int)kb >> 31) | 0x80000000);
                unsigned col = (unsigned)(k0 + cbase + n * 16 + lrow);
                unsigned long long pk = (((unsigned long long)key) << 32) | col;
                best = pk < best ? pk : best;
            }
            #pragma unroll
            for (int mask = 1; mask <= 8; mask <<= 1) {
                unsigned hi = __shfl_xor((unsigned)(best >> 32), mask, 64);
                unsigned lo = __shfl_xor((unsigned)(best & 0xFFFFFFFFu), mask, 64);
                unsigned long long other = (((unsigned long long)hi) << 32) | lo;
                best = other < best ? other : best;
            }
            if (lrow == 0) {
                int grow = n0 + rbase + m * 16 + lk * 4 + r;
                atomicMin(&packed[grow], best);
            }
        }
    }
}

// ---------------- fallback GEMM (in-kernel conversion, round-1 path) -------
__device__ __forceinline__ void stage_tile_fb(const float* __restrict__ src,
                                              unsigned short* __restrict__ Hh,
                                              unsigned short* __restrict__ Hl,
                                              int t) {
    int rsub = t >> 4;
    int f4i  = t & 15;
    int g    = f4i >> 1;
    int off  = (f4i & 1) * 4;
    #pragma unroll
    for (int p = 0; p < 8; p++) {
        int row = p * 16 + rsub;
        float4 v = *(const float4*)(src + (size_t)row * DIM + f4i * 4);
        ushort4 h, l;
        float f;
        f = v.x; h.x = f2bf_rn(f); l.x = f2bf_rn(f - bf2f(h.x));
        f = v.y; h.y = f2bf_rn(f); l.y = f2bf_rn(f - bf2f(h.y));
        f = v.z; h.z = f2bf_rn(f); l.z = f2bf_rn(f - bf2f(h.z));
        f = v.w; h.w = f2bf_rn(f); l.w = f2bf_rn(f - bf2f(h.w));
        int sg  = g ^ (row & 7);
        int idx = row * 64 + sg * 8 + off;
        *(ushort4*)(Hh + idx) = h;
        *(ushort4*)(Hl + idx) = l;
    }
}

__global__ __launch_bounds__(256, 2)
void gemm_argmin_fb(const float* __restrict__ X, const float* __restrict__ C,
                    const float* __restrict__ csq,
                    unsigned long long* __restrict__ packed) {
    __shared__ unsigned short AhL[128 * 64];
    __shared__ unsigned short AlL[128 * 64];
    __shared__ unsigned short BhL[128 * 64];
    __shared__ unsigned short BlL[128 * 64];

    int b = blockIdx.x;
    int x = b & 7;
    int m8 = b >> 3;
    int rowtile = x * 64 + (m8 >> 3);
    int coltile = m8 & 7;
    int n0 = rowtile * 128;
    int k0 = coltile * 128;

    int t    = threadIdx.x;
    int w    = t >> 6;
    int lane = t & 63;
    int wr   = w >> 1, wc = w & 1;
    int rbase = wr * 64, cbase = wc * 64;
    int lrow = lane & 15;
    int lk   = lane >> 4;

    f32x4 acc[4][4];
    #pragma unroll
    for (int i = 0; i < 4; i++)
        #pragma unroll
        for (int j = 0; j < 4; j++)
            acc[i][j] = (f32x4){0.f, 0.f, 0.f, 0.f};

    for (int d0 = 0; d0 < DIM; d0 += 64) {
        stage_tile_fb(X + (size_t)n0 * DIM + d0, AhL, AlL, t);
        stage_tile_fb(C + (size_t)k0 * DIM + d0, BhL, BlL, t);
        __syncthreads();

        #pragma unroll
        for (int kk = 0; kk < 2; kk++) {
            int gidx = kk * 4 + lk;
            bf16x8 ah[4], al[4], bh[4], bl[4];
            #pragma unroll
            for (int m = 0; m < 4; m++) {
                int row = rbase + m * 16 + lrow;
                int sg  = gidx ^ (row & 7);
                ah[m] = *(const bf16x8*)&AhL[row * 64 + sg * 8];
                al[m] = *(const bf16x8*)&AlL[row * 64 + sg * 8];
            }
            #pragma unroll
            for (int n = 0; n < 4; n++) {
                int col = cbase + n * 16 + lrow;
                int sg  = gidx ^ (col & 7);
                bh[n] = *(const bf16x8*)&BhL[col * 64 + sg * 8];
                bl[n] = *(const bf16x8*)&BlL[col * 64 + sg * 8];
            }
            #pragma unroll
            for (int m = 0; m < 4; m++)
                #pragma unroll
                for (int n = 0; n < 4; n++) {
                    acc[m][n] = __builtin_amdgcn_mfma_f32_16x16x32_bf16(ah[m], bh[n], acc[m][n], 0, 0, 0);
                    acc[m][n] = __builtin_amdgcn_mfma_f32_16x16x32_bf16(ah[m], bl[n], acc[m][n], 0, 0, 0);
                    acc[m][n] = __builtin_amdgcn_mfma_f32_16x16x32_bf16(al[m], bh[n], acc[m][n], 0, 0, 0);
                }
        }
        __syncthreads();
    }

    float cs[4];
    #pragma unroll
    for (int n = 0; n < 4; n++) cs[n] = csq[k0 + cbase + n * 16 + lrow];

    #pragma unroll
    for (int m = 0; m < 4; m++) {
        #pragma unroll
        for (int r = 0; r < 4; r++) {
            unsigned long long best = ~0ull;
            #pragma unroll
            for (int n = 0; n < 4; n++) {
                float s = cs[n] - 2.0f * acc[m][n][r];
                unsigned kb  = __float_as_uint(s);
                unsigned key = kb ^ (unsigned)(((int)kb >> 31) | 0x80000000);
                unsigned col = (unsigned)(k0 + cbase + n * 16 + lrow);
                unsigned long long pk = (((unsigned long long)key) << 32) | col;
                best = pk < best ? pk : best;
            }
            #pragma unroll
            for (int mask = 1; mask <= 8; mask <<= 1) {
                unsigned hi = __shfl_xor((unsigned)(best >> 32), mask, 64);
                unsigned lo = __shfl_xor((unsigned)(best & 0xFFFFFFFFu), mask, 64);
                unsigned long long other = (((unsigned long long)hi) << 32) | lo;
                best = other < best ? other : best;
            }
            if (lrow == 0) {
                int grow = n0 + rbase + m * 16 + lk * 4 + r;
                atomicMin(&packed[grow], best);
            }
        }
    }
}

// ---------------- winner -> class ----------------
__global__ void map_kernel(const unsigned long long* __restrict__ packed,
                           const int* __restrict__ classes,
                           int* __restrict__ out) {
    int n = blockIdx.x * 256 + threadIdx.x;
    if (n < N_ROWS) {
        unsigned col = (unsigned)(packed[n] & 0xFFFFFFFFull);
        out[n] = classes[col];
    }
}

extern "C" void kernel_launch(void* const* d_in, const int* in_sizes, int n_in,
                              void* d_out, int out_size, void* d_ws, size_t ws_size,
                              hipStream_t stream) {
    const float* X       = (const float*)d_in[0];
    const float* C       = (const float*)d_in[1];
    const int*   classes = (const int*)d_in[2];
    int*         out     = (int*)d_out;

    char* ws = (char*)d_ws;
    size_t off = 0;
    unsigned long long* packed = (unsigned long long*)(ws + off); off += (size_t)N_ROWS * 8;
    float* csq = (float*)(ws + off);                              off += (size_t)K_CB * 4;
    unsigned short* Xh = (unsigned short*)(ws + off);             off += (size_t)N_ROWS * DIM * 2;
    unsigned short* Xl = (unsigned short*)(ws + off);             off += (size_t)N_ROWS * DIM * 2;
    unsigned short* Ch = (unsigned short*)(ws + off);             off += (size_t)K_CB * DIM * 2;
    unsigned short* Cl = (unsigned short*)(ws + off);             off += (size_t)K_CB * DIM * 2;

    init_kernel<<<N_ROWS / 256, 256, 0, stream>>>(packed);
    csq_kernel<<<K_CB / 4, 256, 0, stream>>>(C, csq);

    if (ws_size >= off) {
        split_kernel<<<2048, 256, 0, stream>>>(X, Xh, Xl, N_ROWS * DIM / 4);
        split_kernel<<<512, 256, 0, stream>>>(C, Ch, Cl, K_CB * DIM / 4);
        hipFuncSetAttribute((const void*)gemm_argmin,
                            hipFuncAttributeMaxDynamicSharedMemorySize,
                            2 * LDSBUF * sizeof(unsigned short));
        gemm_argmin<<<(N_ROWS / 256) * (K_CB / 256), 512,
                      2 * LDSBUF * sizeof(unsigned short), stream>>>(
            Xh, Xl, Ch, Cl, csq, packed);
    } else {
        gemm_argmin_fb<<<(N_ROWS / 128) * (K_CB / 128), 256, 0, stream>>>(X, C, csq, packed);
    }
    map_kernel<<<N_ROWS / 256, 256, 0, stream>>>(packed, classes, out);
}

// Round 11
// 191.591 us; speedup vs baseline: 1.3734x; 1.3245x over previous
//
#include <hip/hip_runtime.h>
#include <hip/hip_bf16.h>

// LVQ: out[n] = classes[argmin_k ||x_n - c_k||^2]
// N=65536, D=512, K=1024, classes int32.
//
// Round 11: approximate-then-certify (r10 structure, phase-2 UB fixed).
//  Phase 1: 1-pass bf16 MFMA GEMM (r9's proven 256x256 schedule, half the
//    arrays) stores cross[n][k] in fp16 (ws).
//  Phase 2: wave-per-row: approx-min over stored scores, shortlist within
//    THR=16 (worst-case |approx-exact| <= 5.6 => 2*5.6 = 11.2 < 16), exact
//    fp32 rescore of shortlist (typically 1-2 candidates). Singleton
//    shortlist certifies with no exact work.
//  r10 bug: (&q0.x)[4..7] read past a local float4 (UB) -> garbage csq for
//    half the columns. Fixed with explicit component unpack into q[16].
//  Fallback (ws too small): round-9 3-pass bf16-split path (verified).

#define N_ROWS 65536
#define DIM    512
#define K_CB   1024
#define NT     16          // DIM / BK, BK=32
#define LDSBUF_F 16384     // fast gemm buffer elems: Ah|Bh = 2 x 8192 (32 KB)
#define LDSBUF   32768     // fallback r9 buffer elems

typedef short bf16x8 __attribute__((ext_vector_type(8)));
typedef float f32x4  __attribute__((ext_vector_type(4)));

__device__ __forceinline__ unsigned short f2bf_rn(float f) {
    unsigned u = __float_as_uint(f);
    unsigned r = (u + 0x7FFFu + ((u >> 16) & 1u)) >> 16;
    return (unsigned short)r;
}
__device__ __forceinline__ float bf2f(unsigned short h) {
    return __uint_as_float(((unsigned)h) << 16);
}

__device__ __forceinline__ void gload16(const void* g, void* l) {
    __builtin_amdgcn_global_load_lds(
        (const __attribute__((address_space(1))) unsigned int*)g,
        (__attribute__((address_space(3))) unsigned int*)l, 16, 0, 0);
}

// ---------------- csq[k] = sum_d C[k][d]^2 (fp32) ----------------
__global__ void csq_kernel(const float* __restrict__ C, float* __restrict__ csq) {
    int wid  = (blockIdx.x * blockDim.x + threadIdx.x) >> 6;   // one wave per k
    int lane = threadIdx.x & 63;
    const float4* p = (const float4*)(C + (size_t)wid * DIM);
    float4 a = p[lane * 2];
    float4 b = p[lane * 2 + 1];
    float s = a.x*a.x + a.y*a.y + a.z*a.z + a.w*a.w
            + b.x*b.x + b.y*b.y + b.z*b.z + b.w*b.w;
    #pragma unroll
    for (int m = 1; m < 64; m <<= 1) s += __shfl_xor(s, m, 64);
    if (lane == 0) csq[wid] = s;
}

// ---------------- fp32 -> bf16 (hi only, RN) ----------------
__global__ void split_hi(const float* __restrict__ src,
                         unsigned short* __restrict__ h, int n4) {
    int stride = gridDim.x * 256;
    for (int i = blockIdx.x * 256 + threadIdx.x; i < n4; i += stride) {
        float4 v = ((const float4*)src)[i];
        ushort4 hh;
        hh.x = f2bf_rn(v.x); hh.y = f2bf_rn(v.y);
        hh.z = f2bf_rn(v.z); hh.w = f2bf_rn(v.w);
        ((ushort4*)h)[i] = hh;
    }
}

// ---------------- Phase 1: 1-pass bf16 GEMM -> fp16 cross ------------------
// r9's verified 256x256 BK=32 skeleton, arrays halved (Ah|Bh only).
// LDS per buffer: Ah[0,8192) Bh[8192,16384); [row][group 0..3][8 elems];
// LDS[row][g] holds GLOBAL k-group g ^ ((row>>1)&3) (source-side swizzle,
// linear gload_lds dest; 0 conflicts verified r2-r9).
__global__ __launch_bounds__(512, 2)
void gemm_cross(const unsigned short* __restrict__ Xh,
                const unsigned short* __restrict__ Ch,
                _Float16* __restrict__ cross) {
    extern __shared__ unsigned short smem[];   // 2 * LDSBUF_F elements (64 KB)

    int b  = blockIdx.x;
    int x  = b & 7;
    int m8 = b >> 3;                   // 0..127
    int rowtile = x * 32 + (m8 >> 2);  // 0..255
    int coltile = m8 & 3;              // 0..3
    int n0 = rowtile * 256;
    int k0 = coltile * 256;

    int tid  = threadIdx.x;
    int w    = tid >> 6;
    int lane = tid & 63;
    int wr   = w >> 2, wc = w & 3;     // 2M x 4N waves; wave tile 128x64
    int rbase = wr * 128, cbase = wc * 64;
    int lrow = lane & 15;
    int lk   = lane >> 4;
    int sg   = lk ^ ((lrow >> 1) & 3);

    int srow = tid >> 2;               // 0..127
    int sgrp = tid & 3;
    int r1   = (srow < 64) ? srow : srow + 64;     // A rows {0-63,128-191}
    int ggA  = sgrp ^ ((r1 >> 1) & 3);
    int gB   = sgrp ^ ((srow >> 1) & 3);
    size_t oA1 = (size_t)(n0 + r1) * DIM + ggA * 8;
    size_t oA2 = oA1 + (size_t)64 * DIM;
    size_t oB0 = (size_t)(k0 + srow) * DIM + gB * 8;
    size_t oB1 = oB0 + (size_t)128 * DIM;
    int rowA1_0 = (w < 4) ? w * 16 : w * 16 + 64;
    int dA1  = rowA1_0 * 32;
    int dA2  = dA1 + 2048;
    int dB0  = 8192 + w * 512;
    int dB1  = dB0 + 4096;

    f32x4 acc[8][4];
    #pragma unroll
    for (int i = 0; i < 8; i++)
        #pragma unroll
        for (int j = 0; j < 4; j++)
            acc[i][j] = (f32x4){0.f, 0.f, 0.f, 0.f};

    auto issue_tile = [&](int t) {
        unsigned short* bufn = smem + (t & 1) * LDSBUF_F;
        size_t d = (size_t)t * 32;
        gload16(Xh + oA1 + d, bufn + dA1);
        gload16(Xh + oA2 + d, bufn + dA2);
        gload16(Ch + oB0 + d, bufn + dB0);
        gload16(Ch + oB1 + d, bufn + dB1);
    };

    issue_tile(0);

    for (int t = 0; t < NT; ++t) {
        // tile t's 4 loads were issued a full tile of MFMA ago -> cheap drain
        asm volatile("s_waitcnt vmcnt(0)" ::: "memory");
        __builtin_amdgcn_s_barrier();
        asm volatile("" ::: "memory");

        const unsigned short* buf = smem + (t & 1) * LDSBUF_F;
        const unsigned short* pA = buf + (rbase + lrow) * 32 + sg * 8;
        const unsigned short* pB = buf + 8192 + (cbase + lrow) * 32 + sg * 8;

        bf16x8 bh[4], ah[8];
        #pragma unroll
        for (int n = 0; n < 4; n++) bh[n] = *(const bf16x8*)(pB + n * 512);
        #pragma unroll
        for (int m = 0; m < 8; m++) ah[m] = *(const bf16x8*)(pA + m * 512);
        if (t + 1 < NT) issue_tile(t + 1);

        __builtin_amdgcn_s_setprio(1);
        // 32 fully independent MFMAs (each acc touched once per tile)
        #pragma unroll
        for (int m = 0; m < 8; m++)
            #pragma unroll
            for (int n = 0; n < 4; n++)
                acc[m][n] = __builtin_amdgcn_mfma_f32_16x16x32_bf16(ah[m], bh[n], acc[m][n], 0, 0, 0);
        __builtin_amdgcn_s_setprio(0);
    }

    // epilogue: store fp16 cross. C/D: col=lane&15, row=(lane>>4)*4+reg.
    #pragma unroll
    for (int m = 0; m < 8; m++) {
        int grow = n0 + rbase + m * 16 + lk * 4;
        #pragma unroll
        for (int r = 0; r < 4; r++) {
            _Float16* cp = cross + (size_t)(grow + r) * K_CB + k0 + cbase + lrow;
            #pragma unroll
            for (int n = 0; n < 4; n++)
                cp[n * 16] = (_Float16)acc[m][n][r];
        }
    }
}

// ---------------- Phase 2: shortlist + exact certify ----------------
// approx score_k = csq[k] - 2*(float)cross16[n][k].
// Worst case |approx-exact| <= 2*(2^-9*2*||x||*||c|| + fp16 store ulp)
// <= 5.6 =: D. THR=16 > 2*D: the exact argmin is always in
// {k: approx_k <= min_approx + THR}; a singleton shortlist is provably
// optimal without rescore. Typical D ~ 1, so THR=16 is very safe.
struct H8 { _Float16 v[8]; };

__global__ __launch_bounds__(256)
void phase2_kernel(const float* __restrict__ X, const float* __restrict__ C,
                   const float* __restrict__ csq,
                   const _Float16* __restrict__ cross,
                   const int* __restrict__ classes, int* __restrict__ out) {
    int lane = threadIdx.x & 63;
    int n = blockIdx.x * 4 + (threadIdx.x >> 6);   // one wave per row

    // 16 fp16 cross values per lane (UB-free unpack)
    float cr[16];
    {
        const _Float16* cp16 = cross + (size_t)n * K_CB + lane * 16;
        H8 h0 = *(const H8*)cp16;
        H8 h1 = *(const H8*)(cp16 + 8);
        #pragma unroll
        for (int j = 0; j < 8; j++) {
            cr[j]     = (float)h0.v[j];
            cr[8 + j] = (float)h1.v[j];
        }
    }
    // 16 csq values per lane (UB-free unpack)
    float q[16];
    {
        const float4* qp = (const float4*)(csq + lane * 16);
        float4 a0 = qp[0], a1 = qp[1], a2 = qp[2], a3 = qp[3];
        q[0]=a0.x;  q[1]=a0.y;  q[2]=a0.z;  q[3]=a0.w;
        q[4]=a1.x;  q[5]=a1.y;  q[6]=a1.z;  q[7]=a1.w;
        q[8]=a2.x;  q[9]=a2.y;  q[10]=a2.z; q[11]=a2.w;
        q[12]=a3.x; q[13]=a3.y; q[14]=a3.z; q[15]=a3.w;
    }

    float s[16];
    #pragma unroll
    for (int j = 0; j < 16; j++) s[j] = q[j] - 2.0f * cr[j];

    float mn = s[0];
    #pragma unroll
    for (int j = 1; j < 16; j++) mn = fminf(mn, s[j]);
    #pragma unroll
    for (int m = 1; m < 64; m <<= 1) mn = fminf(mn, __shfl_xor(mn, m, 64));

    float thr = mn + 16.0f;
    unsigned fl = 0;
    #pragma unroll
    for (int j = 0; j < 16; j++) fl |= (unsigned)(s[j] <= thr) << j;
    int cnt = __popc(fl);
    #pragma unroll
    for (int m = 1; m < 64; m <<= 1) cnt += __shfl_xor(cnt, m, 64);

    int bestk;
    if (cnt == 1) {
        int kk = 0x7fffffff;
        #pragma unroll
        for (int j = 0; j < 16; j++)
            if ((fl >> j) & 1) kk = lane * 16 + j;
        #pragma unroll
        for (int m = 1; m < 64; m <<= 1) kk = min(kk, __shfl_xor(kk, m, 64));
        bestk = kk;
    } else {
        const float4* xp = (const float4*)(X + (size_t)n * DIM + lane * 8);
        float4 x0 = xp[0], x1 = xp[1];
        float bv = 3.4e38f;
        int bk = 0x7fffffff;
        #pragma unroll 1
        for (int j = 0; j < 16; j++) {
            unsigned long long mask = __ballot((fl >> j) & 1);
            while (mask) {
                int l = __ffsll((unsigned long long)mask) - 1;
                mask &= mask - 1;
                int k = l * 16 + j;                       // wave-uniform
                const float4* cp = (const float4*)(C + (size_t)k * DIM + lane * 8);
                float4 y0 = cp[0], y1 = cp[1];
                float d = x0.x*y0.x + x0.y*y0.y + x0.z*y0.z + x0.w*y0.w
                        + x1.x*y1.x + x1.y*y1.y + x1.z*y1.z + x1.w*y1.w;
                #pragma unroll
                for (int m = 1; m < 64; m <<= 1) d += __shfl_xor(d, m, 64);
                float se = csq[k] - 2.0f * d;             // exact fp32 score
                if (se < bv || (se == bv && k < bk)) { bv = se; bk = k; }
            }
        }
        bestk = bk;
    }
    if (lane == 0) out[n] = classes[bestk];
}

// ======================= fallback path (round-9, verified) =================
__global__ void init_kernel(unsigned long long* __restrict__ packed) {
    int n = blockIdx.x * 256 + threadIdx.x;
    if (n < N_ROWS) packed[n] = ~0ull;
}

__global__ void split_kernel(const float* __restrict__ src,
                             unsigned short* __restrict__ h,
                             unsigned short* __restrict__ l, int n4) {
    int stride = gridDim.x * 256;
    for (int i = blockIdx.x * 256 + threadIdx.x; i < n4; i += stride) {
        float4 v = ((const float4*)src)[i];
        ushort4 hh, ll;
        float f;
        f = v.x; hh.x = f2bf_rn(f); ll.x = f2bf_rn(f - bf2f(hh.x));
        f = v.y; hh.y = f2bf_rn(f); ll.y = f2bf_rn(f - bf2f(hh.y));
        f = v.z; hh.z = f2bf_rn(f); ll.z = f2bf_rn(f - bf2f(hh.z));
        f = v.w; hh.w = f2bf_rn(f); ll.w = f2bf_rn(f - bf2f(hh.w));
        ((ushort4*)h)[i] = hh;
        ((ushort4*)l)[i] = ll;
    }
}

__global__ __launch_bounds__(512, 2)
void gemm_argmin(const unsigned short* __restrict__ Xh,
                 const unsigned short* __restrict__ Xl,
                 const unsigned short* __restrict__ Ch,
                 const unsigned short* __restrict__ Cl,
                 const float* __restrict__ csq,
                 unsigned long long* __restrict__ packed) {
    extern __shared__ unsigned short smem[];   // 2 * LDSBUF elements (128 KB)

    int b  = blockIdx.x;
    int x  = b & 7;
    int m8 = b >> 3;
    int rowtile = x * 32 + (m8 >> 2);
    int coltile = m8 & 3;
    int n0 = rowtile * 256;
    int k0 = coltile * 256;

    int tid  = threadIdx.x;
    int w    = tid >> 6;
    int lane = tid & 63;
    int wr   = w >> 2, wc = w & 3;
    int rbase = wr * 128, cbase = wc * 64;
    int lrow = lane & 15;
    int lk   = lane >> 4;
    int sg   = lk ^ ((lrow >> 1) & 3);

    int srow = tid >> 2;
    int sgrp = tid & 3;
    int r1   = (srow < 64) ? srow : srow + 64;
    int ggA  = sgrp ^ ((r1 >> 1) & 3);
    int gB   = sgrp ^ ((srow >> 1) & 3);
    size_t oA1 = (size_t)(n0 + r1) * DIM + ggA * 8;
    size_t oA2 = oA1 + (size_t)64 * DIM;
    size_t oB0 = (size_t)(k0 + srow) * DIM + gB * 8;
    size_t oB1 = oB0 + (size_t)128 * DIM;
    int rowA1_0 = (w < 4) ? w * 16 : w * 16 + 64;
    int dA1  = rowA1_0 * 32;
    int dA2  = dA1 + 2048;
    int dB0  = 16384 + w * 512;
    int dB1  = dB0 + 4096;
    int dBl0 = dB0 + 8192;
    int dBl1 = dB1 + 8192;

    f32x4 acc[8][4];
    #pragma unroll
    for (int i = 0; i < 8; i++)
        #pragma unroll
        for (int j = 0; j < 4; j++)
            acc[i][j] = (f32x4){0.f, 0.f, 0.f, 0.f};

    bf16x8 bh[4], bl[4];

    auto issue_tile = [&](int t) {
        unsigned short* bufn = smem + (t & 1) * LDSBUF;
        size_t d = (size_t)t * 32;
        gload16(Xh + oA1 + d, bufn + dA1);
        gload16(Xl + oA1 + d, bufn + 8192 + dA1);
        gload16(Ch + oB0 + d, bufn + dB0);
        gload16(Ch + oB1 + d, bufn + dB1);
        gload16(Cl + oB0 + d, bufn + dBl0);
        gload16(Cl + oB1 + d, bufn + dBl1);
        gload16(Xh + oA2 + d, bufn + dA2);
        gload16(Xl + oA2 + d, bufn + 8192 + dA2);
    };

    auto mfma_half = [&](int mb, const bf16x8* ah, const bf16x8* al) {
        __builtin_amdgcn_s_setprio(1);
        #pragma unroll
        for (int mm = 0; mm < 4; mm++)
            #pragma unroll
            for (int n = 0; n < 4; n++)
                acc[mb + mm][n] = __builtin_amdgcn_mfma_f32_16x16x32_bf16(ah[mm], bh[n], acc[mb + mm][n], 0, 0, 0);
        #pragma unroll
        for (int mm = 0; mm < 4; mm++)
            #pragma unroll
            for (int n = 0; n < 4; n++)
                acc[mb + mm][n] = __builtin_amdgcn_mfma_f32_16x16x32_bf16(ah[mm], bl[n], acc[mb + mm][n], 0, 0, 0);
        #pragma unroll
        for (int mm = 0; mm < 4; mm++)
            #pragma unroll
            for (int n = 0; n < 4; n++)
                acc[mb + mm][n] = __builtin_amdgcn_mfma_f32_16x16x32_bf16(al[mm], bh[n], acc[mb + mm][n], 0, 0, 0);
        __builtin_amdgcn_s_setprio(0);
    };

    issue_tile(0);

    for (int t = 0; t < NT; ++t) {
        asm volatile("s_waitcnt vmcnt(0)" ::: "memory");
        __builtin_amdgcn_s_barrier();
        asm volatile("" ::: "memory");

        const unsigned short* buf = smem + (t & 1) * LDSBUF;
        const unsigned short* pA = buf + (rbase + lrow) * 32 + sg * 8;
        const unsigned short* pB = buf + 16384 + (cbase + lrow) * 32 + sg * 8;

        #pragma unroll
        for (int n = 0; n < 4; n++) {
            bh[n] = *(const bf16x8*)(pB + n * 512);
            bl[n] = *(const bf16x8*)(pB + 8192 + n * 512);
        }
        bf16x8 ah[4], al[4];
        #pragma unroll
        for (int mm = 0; mm < 4; mm++) {
            ah[mm] = *(const bf16x8*)(pA + mm * 512);
            al[mm] = *(const bf16x8*)(pA + 8192 + mm * 512);
        }
        if (t + 1 < NT) issue_tile(t + 1);

        mfma_half(0, ah, al);

        bf16x8 ah2[4], al2[4];
        #pragma unroll
        for (int mm = 0; mm < 4; mm++) {
            ah2[mm] = *(const bf16x8*)(pA + (4 + mm) * 512);
            al2[mm] = *(const bf16x8*)(pA + 8192 + (4 + mm) * 512);
        }
        mfma_half(4, ah2, al2);
    }

    float cs[4];
    #pragma unroll
    for (int n = 0; n < 4; n++) cs[n] = csq[k0 + cbase + n * 16 + lrow];

    #pragma unroll
    for (int m = 0; m < 8; m++) {
        #pragma unroll
        for (int r = 0; r < 4; r++) {
            unsigned long long best = ~0ull;
            #pragma unroll
            for (int n = 0; n < 4; n++) {
                float s = cs[n] - 2.0f * acc[m][n][r];
                unsigned kb  = __float_as_uint(s);
                unsigned key = kb ^ (unsigned)(((int)kb >> 31) | 0x80000000);
                unsigned col = (unsigned)(k0 + cbase + n * 16 + lrow);
                unsigned long long pk = (((unsigned long long)key) << 32) | col;
                best = pk < best ? pk : best;
            }
            #pragma unroll
            for (int mask = 1; mask <= 8; mask <<= 1) {
                unsigned hi = __shfl_xor((unsigned)(best >> 32), mask, 64);
                unsigned lo = __shfl_xor((unsigned)(best & 0xFFFFFFFFu), mask, 64);
                unsigned long long other = (((unsigned long long)hi) << 32) | lo;
                best = other < best ? other : best;
            }
            if (lrow == 0) {
                int grow = n0 + rbase + m * 16 + lk * 4 + r;
                atomicMin(&packed[grow], best);
            }
        }
    }
}

__global__ void map_kernel(const unsigned long long* __restrict__ packed,
                           const int* __restrict__ classes,
                           int* __restrict__ out) {
    int n = blockIdx.x * 256 + threadIdx.x;
    if (n < N_ROWS) {
        unsigned col = (unsigned)(packed[n] & 0xFFFFFFFFull);
        out[n] = classes[col];
    }
}

extern "C" void kernel_launch(void* const* d_in, const int* in_sizes, int n_in,
                              void* d_out, int out_size, void* d_ws, size_t ws_size,
                              hipStream_t stream) {
    const float* X       = (const float*)d_in[0];
    const float* C       = (const float*)d_in[1];
    const int*   classes = (const int*)d_in[2];
    int*         out     = (int*)d_out;
    char* ws = (char*)d_ws;

    // ---- fast path layout: csq | Xh | Ch | cross(fp16) ----
    {
        size_t off = 0;
        float* csq = (float*)(ws + off);               off += 4096;
        unsigned short* Xh = (unsigned short*)(ws + off); off += (size_t)N_ROWS * DIM * 2;
        unsigned short* Ch = (unsigned short*)(ws + off); off += (size_t)K_CB * DIM * 2;
        _Float16* cross = (_Float16*)(ws + off);       off += (size_t)N_ROWS * K_CB * 2;
        if (ws_size >= off) {
            csq_kernel<<<K_CB / 4, 256, 0, stream>>>(C, csq);
            split_hi<<<2048, 256, 0, stream>>>(X, Xh, N_ROWS * DIM / 4);
            split_hi<<<512, 256, 0, stream>>>(C, Ch, K_CB * DIM / 4);
            hipFuncSetAttribute((const void*)gemm_cross,
                                hipFuncAttributeMaxDynamicSharedMemorySize,
                                2 * LDSBUF_F * (int)sizeof(unsigned short));
            gemm_cross<<<(N_ROWS / 256) * (K_CB / 256), 512,
                         2 * LDSBUF_F * sizeof(unsigned short), stream>>>(Xh, Ch, cross);
            phase2_kernel<<<N_ROWS / 4, 256, 0, stream>>>(X, C, csq, cross, classes, out);
            return;
        }
    }

    // ---- fallback: round-9 3-pass path ----
    size_t off = 0;
    unsigned long long* packed = (unsigned long long*)(ws + off); off += (size_t)N_ROWS * 8;
    float* csq = (float*)(ws + off);                              off += (size_t)K_CB * 4;
    unsigned short* Xh = (unsigned short*)(ws + off);             off += (size_t)N_ROWS * DIM * 2;
    unsigned short* Xl = (unsigned short*)(ws + off);             off += (size_t)N_ROWS * DIM * 2;
    unsigned short* Ch = (unsigned short*)(ws + off);             off += (size_t)K_CB * DIM * 2;
    unsigned short* Cl = (unsigned short*)(ws + off);             off += (size_t)K_CB * DIM * 2;

    init_kernel<<<N_ROWS / 256, 256, 0, stream>>>(packed);
    csq_kernel<<<K_CB / 4, 256, 0, stream>>>(C, csq);
    split_kernel<<<2048, 256, 0, stream>>>(X, Xh, Xl, N_ROWS * DIM / 4);
    split_kernel<<<512, 256, 0, stream>>>(C, Ch, Cl, K_CB * DIM / 4);
    hipFuncSetAttribute((const void*)gemm_argmin,
                        hipFuncAttributeMaxDynamicSharedMemorySize,
                        2 * LDSBUF * (int)sizeof(unsigned short));
    gemm_argmin<<<(N_ROWS / 256) * (K_CB / 256), 512,
                  2 * LDSBUF * sizeof(unsigned short), stream>>>(
        Xh, Xl, Ch, Cl, csq, packed);
    map_kernel<<<N_ROWS / 256, 256, 0, stream>>>(packed, classes, out);
}

// Round 12
// 168.177 us; speedup vs baseline: 1.5646x; 1.1392x over previous
//
#include <hip/hip_runtime.h>
#include <hip/hip_bf16.h>

// LVQ: out[n] = classes[argmin_k ||x_n - c_k||^2]
// N=65536, D=512, K=1024, classes int32.
//
// Round 12: approximate-then-certify, split_X eliminated.
//  Phase 1 (gemm_scores): 1-pass bf16 MFMA GEMM. A (=X) is reg-staged:
//    fp32 loaded to VGPRs one tile ahead, converted in-kernel, ds_write to
//    the swizzled LDS layout (ds_write allows swizzled dests; uniform
//    bank spread). B (=C) pre-split to bf16 (1 MB) and staged by
//    global_load_lds with source-side swizzle (r11-verified). Epilogue
//    stores score = csq - 2*cross as fp16.
//  Phase 2: wave-per-row: approx min over stored scores, shortlist within
//    THR=16 (rigorous: 2*Dmax = 11 < 16), exact fp32 rescore of shortlist.
//  Fallback (ws too small): round-9 3-pass bf16-split path (verified).

#define N_ROWS 65536
#define DIM    512
#define K_CB   1024
#define NT     16          // DIM / BK, BK=32
#define LDSBUF_F 16384     // fast gemm buffer elems: A[0,8192)|B[8192,16384)
#define LDSBUF   32768     // fallback r9 buffer elems

typedef short bf16x8 __attribute__((ext_vector_type(8)));
typedef float f32x4  __attribute__((ext_vector_type(4)));

__device__ __forceinline__ unsigned short f2bf_rn(float f) {
    unsigned u = __float_as_uint(f);
    unsigned r = (u + 0x7FFFu + ((u >> 16) & 1u)) >> 16;
    return (unsigned short)r;
}
__device__ __forceinline__ float bf2f(unsigned short h) {
    return __uint_as_float(((unsigned)h) << 16);
}
__device__ __forceinline__ bf16x8 pack_bf8(float4 a, float4 b) {
    bf16x8 r;
    r[0] = (short)f2bf_rn(a.x); r[1] = (short)f2bf_rn(a.y);
    r[2] = (short)f2bf_rn(a.z); r[3] = (short)f2bf_rn(a.w);
    r[4] = (short)f2bf_rn(b.x); r[5] = (short)f2bf_rn(b.y);
    r[6] = (short)f2bf_rn(b.z); r[7] = (short)f2bf_rn(b.w);
    return r;
}

__device__ __forceinline__ void gload16(const void* g, void* l) {
    __builtin_amdgcn_global_load_lds(
        (const __attribute__((address_space(1))) unsigned int*)g,
        (__attribute__((address_space(3))) unsigned int*)l, 16, 0, 0);
}

// ---------------- csq[k] = sum_d C[k][d]^2 (fp32) ----------------
__global__ void csq_kernel(const float* __restrict__ C, float* __restrict__ csq) {
    int wid  = (blockIdx.x * blockDim.x + threadIdx.x) >> 6;   // one wave per k
    int lane = threadIdx.x & 63;
    const float4* p = (const float4*)(C + (size_t)wid * DIM);
    float4 a = p[lane * 2];
    float4 b = p[lane * 2 + 1];
    float s = a.x*a.x + a.y*a.y + a.z*a.z + a.w*a.w
            + b.x*b.x + b.y*b.y + b.z*b.z + b.w*b.w;
    #pragma unroll
    for (int m = 1; m < 64; m <<= 1) s += __shfl_xor(s, m, 64);
    if (lane == 0) csq[wid] = s;
}

// ---------------- fp32 -> bf16 (hi only, RN) ----------------
__global__ void split_hi(const float* __restrict__ src,
                         unsigned short* __restrict__ h, int n4) {
    int stride = gridDim.x * 256;
    for (int i = blockIdx.x * 256 + threadIdx.x; i < n4; i += stride) {
        float4 v = ((const float4*)src)[i];
        ushort4 hh;
        hh.x = f2bf_rn(v.x); hh.y = f2bf_rn(v.y);
        hh.z = f2bf_rn(v.z); hh.w = f2bf_rn(v.w);
        ((ushort4*)h)[i] = hh;
    }
}

// ---------------- Phase 1: 1-pass bf16 GEMM -> fp16 scores -----------------
// LDS per buffer: A[0,8192) B[8192,16384); [row][group 0..3][8 elems];
// LDS[row][g] holds GLOBAL k-group g^((row>>1)&3).
// A: reg-staged fp32 (linear coalesced source), cvt, ds_write to swizzled
//    dest. B: global_load_lds with source-side swizzle, linear dest.
// Fragment reads use the same XOR (0 conflicts verified r2-r11).
__global__ __launch_bounds__(512, 2)
void gemm_scores(const float* __restrict__ X,
                 const unsigned short* __restrict__ Ch,
                 const float* __restrict__ csq,
                 _Float16* __restrict__ scores) {
    extern __shared__ unsigned short smem[];   // 2 * LDSBUF_F elems (64 KB)

    // XCD-aware mapping: 4 col-tiles of one row-tile run on one XCD
    // -> X fp32 tile (512 KB) L2-resident across them; Ch L2-resident.
    int b  = blockIdx.x;
    int x  = b & 7;
    int m8 = b >> 3;                   // 0..127
    int rowtile = x * 32 + (m8 >> 2);  // 0..255
    int coltile = m8 & 3;              // 0..3
    int n0 = rowtile * 256;
    int k0 = coltile * 256;

    int tid  = threadIdx.x;
    int w    = tid >> 6;
    int lane = tid & 63;
    int wr   = w >> 2, wc = w & 3;     // 2M x 4N waves; wave tile 128x64
    int rbase = wr * 128, cbase = wc * 64;
    int lrow = lane & 15;
    int lk   = lane >> 4;
    int sg   = lk ^ ((lrow >> 1) & 3);

    // A staging: thread -> (arow = tid>>1, global groups ag2, ag2+1)
    int arow = tid >> 1;               // 0..255
    int ag2  = (tid & 1) * 2;          // 0 or 2
    int swA  = (arow >> 1) & 3;
    const float* xsrc = X + (size_t)(n0 + arow) * DIM + ag2 * 8;
    int adst0 = arow * 32 + ((ag2    ) ^ swA) * 8;
    int adst1 = arow * 32 + ((ag2 + 1) ^ swA) * 8;

    // B staging via gload_lds: thread -> (srow = tid>>2, sgrp = tid&3)
    int srow = tid >> 2;               // 0..127
    int sgrp = tid & 3;
    int gB   = sgrp ^ ((srow >> 1) & 3);
    size_t oB0 = (size_t)(k0 + srow) * DIM + gB * 8;
    size_t oB1 = oB0 + (size_t)128 * DIM;
    int dB0  = 8192 + w * 512;
    int dB1  = dB0 + 4096;

    f32x4 acc[8][4];
    #pragma unroll
    for (int i = 0; i < 8; i++)
        #pragma unroll
        for (int j = 0; j < 4; j++)
            acc[i][j] = (f32x4){0.f, 0.f, 0.f, 0.f};

    auto issue_B = [&](int tn) {
        unsigned short* bufn = smem + (tn & 1) * LDSBUF_F;
        size_t d = (size_t)tn * 32;
        gload16(Ch + oB0 + d, bufn + dB0);
        gload16(Ch + oB1 + d, bufn + dB1);
    };

    // X(t) regs, double-buffered by loop unroll (static names, rule #20)
    float4 xa0, xa1, xa2, xa3, xb0, xb1, xb2, xb3;
    {
        const float4* xp = (const float4*)xsrc;
        xa0 = xp[0]; xa1 = xp[1]; xa2 = xp[2]; xa3 = xp[3];
    }
    issue_B(0);

    auto body = [&](int t, float4& u0, float4& u1, float4& u2, float4& u3,
                    float4& f0, float4& f1, float4& f2, float4& f3) {
        // X(t) regs + B(t) LDS landed (issued a full tile ago)
        asm volatile("s_waitcnt vmcnt(0)" ::: "memory");
        // cvt + ds_write A(t). Safe: buf[t&1] readers (tile t-2) finished
        // before tile t-1's barrier.
        unsigned short* abuf = smem + (t & 1) * LDSBUF_F;
        *(bf16x8*)(abuf + adst0) = pack_bf8(u0, u1);
        *(bf16x8*)(abuf + adst1) = pack_bf8(u2, u3);
        asm volatile("s_waitcnt lgkmcnt(0)" ::: "memory");
        __builtin_amdgcn_s_barrier();
        asm volatile("" ::: "memory");

        const unsigned short* buf = smem + (t & 1) * LDSBUF_F;
        const unsigned short* pA = buf + (rbase + lrow) * 32 + sg * 8;
        const unsigned short* pB = buf + 8192 + (cbase + lrow) * 32 + sg * 8;
        bf16x8 bh[4], ah[8];
        #pragma unroll
        for (int n = 0; n < 4; n++) bh[n] = *(const bf16x8*)(pB + n * 512);
        #pragma unroll
        for (int m = 0; m < 8; m++) ah[m] = *(const bf16x8*)(pA + m * 512);
        if (t + 1 < NT) {               // after barrier: all waves past t-1
            const float4* xp = (const float4*)(xsrc + (t + 1) * 32);
            f0 = xp[0]; f1 = xp[1]; f2 = xp[2]; f3 = xp[3];
            issue_B(t + 1);
        }
        __builtin_amdgcn_s_setprio(1);
        #pragma unroll
        for (int m = 0; m < 8; m++)
            #pragma unroll
            for (int n = 0; n < 4; n++)
                acc[m][n] = __builtin_amdgcn_mfma_f32_16x16x32_bf16(ah[m], bh[n], acc[m][n], 0, 0, 0);
        __builtin_amdgcn_s_setprio(0);
    };

    for (int tt = 0; tt < NT; tt += 2) {
        body(tt,     xa0, xa1, xa2, xa3, xb0, xb1, xb2, xb3);
        body(tt + 1, xb0, xb1, xb2, xb3, xa0, xa1, xa2, xa3);
    }

    // epilogue: store fp16 SCORES (csq - 2*cross).
    // C/D: col = lane&15, row = (lane>>4)*4 + reg.
    float cs[4];
    #pragma unroll
    for (int n = 0; n < 4; n++) cs[n] = csq[k0 + cbase + n * 16 + lrow];

    #pragma unroll
    for (int m = 0; m < 8; m++) {
        int grow = n0 + rbase + m * 16 + lk * 4;
        #pragma unroll
        for (int r = 0; r < 4; r++) {
            _Float16* sp = scores + (size_t)(grow + r) * K_CB + k0 + cbase + lrow;
            #pragma unroll
            for (int n = 0; n < 4; n++)
                sp[n * 16] = (_Float16)(cs[n] - 2.0f * acc[m][n][r]);
        }
    }
}

// ---------------- Phase 2: shortlist + exact certify ----------------
// stored score_k ~ csq[k] - 2*x.c_k with |err| <= 2*2^-8*||x||*||c||
// + fp16 ulp <= 5.5 =: D. THR=16 > 2*D: exact argmin always in
// {k: s_k <= min_s + THR}; singleton shortlist is provably optimal.
struct H8 { _Float16 v[8]; };

__global__ __launch_bounds__(256)
void phase2_kernel(const float* __restrict__ X, const float* __restrict__ C,
                   const float* __restrict__ csq,
                   const _Float16* __restrict__ scores,
                   const int* __restrict__ classes, int* __restrict__ out) {
    int lane = threadIdx.x & 63;
    int n = blockIdx.x * 4 + (threadIdx.x >> 6);   // one wave per row

    float s[16];
    {
        const _Float16* sp16 = scores + (size_t)n * K_CB + lane * 16;
        H8 h0 = *(const H8*)sp16;
        H8 h1 = *(const H8*)(sp16 + 8);
        #pragma unroll
        for (int j = 0; j < 8; j++) {
            s[j]     = (float)h0.v[j];
            s[8 + j] = (float)h1.v[j];
        }
    }

    float mn = s[0];
    #pragma unroll
    for (int j = 1; j < 16; j++) mn = fminf(mn, s[j]);
    #pragma unroll
    for (int m = 1; m < 64; m <<= 1) mn = fminf(mn, __shfl_xor(mn, m, 64));

    float thr = mn + 16.0f;
    unsigned fl = 0;
    #pragma unroll
    for (int j = 0; j < 16; j++) fl |= (unsigned)(s[j] <= thr) << j;
    int cnt = __popc(fl);
    #pragma unroll
    for (int m = 1; m < 64; m <<= 1) cnt += __shfl_xor(cnt, m, 64);

    int bestk;
    if (cnt == 1) {
        int kk = 0x7fffffff;
        #pragma unroll
        for (int j = 0; j < 16; j++)
            if ((fl >> j) & 1) kk = lane * 16 + j;
        #pragma unroll
        for (int m = 1; m < 64; m <<= 1) kk = min(kk, __shfl_xor(kk, m, 64));
        bestk = kk;
    } else {
        const float4* xp = (const float4*)(X + (size_t)n * DIM + lane * 8);
        float4 x0 = xp[0], x1 = xp[1];
        float bv = 3.4e38f;
        int bk = 0x7fffffff;
        #pragma unroll 1
        for (int j = 0; j < 16; j++) {
            unsigned long long mask = __ballot((fl >> j) & 1);
            while (mask) {
                int l = __ffsll((unsigned long long)mask) - 1;
                mask &= mask - 1;
                int k = l * 16 + j;                       // wave-uniform
                const float4* cp = (const float4*)(C + (size_t)k * DIM + lane * 8);
                float4 y0 = cp[0], y1 = cp[1];
                float d = x0.x*y0.x + x0.y*y0.y + x0.z*y0.z + x0.w*y0.w
                        + x1.x*y1.x + x1.y*y1.y + x1.z*y1.z + x1.w*y1.w;
                #pragma unroll
                for (int m = 1; m < 64; m <<= 1) d += __shfl_xor(d, m, 64);
                float se = csq[k] - 2.0f * d;             // exact fp32 score
                if (se < bv || (se == bv && k < bk)) { bv = se; bk = k; }
            }
        }
        bestk = bk;
    }
    if (lane == 0) out[n] = classes[bestk];
}

// ======================= fallback path (round-9, verified) =================
__global__ void init_kernel(unsigned long long* __restrict__ packed) {
    int n = blockIdx.x * 256 + threadIdx.x;
    if (n < N_ROWS) packed[n] = ~0ull;
}

__global__ void split_kernel(const float* __restrict__ src,
                             unsigned short* __restrict__ h,
                             unsigned short* __restrict__ l, int n4) {
    int stride = gridDim.x * 256;
    for (int i = blockIdx.x * 256 + threadIdx.x; i < n4; i += stride) {
        float4 v = ((const float4*)src)[i];
        ushort4 hh, ll;
        float f;
        f = v.x; hh.x = f2bf_rn(f); ll.x = f2bf_rn(f - bf2f(hh.x));
        f = v.y; hh.y = f2bf_rn(f); ll.y = f2bf_rn(f - bf2f(hh.y));
        f = v.z; hh.z = f2bf_rn(f); ll.z = f2bf_rn(f - bf2f(hh.z));
        f = v.w; hh.w = f2bf_rn(f); ll.w = f2bf_rn(f - bf2f(hh.w));
        ((ushort4*)h)[i] = hh;
        ((ushort4*)l)[i] = ll;
    }
}

__global__ __launch_bounds__(512, 2)
void gemm_argmin(const unsigned short* __restrict__ Xh,
                 const unsigned short* __restrict__ Xl,
                 const unsigned short* __restrict__ Ch,
                 const unsigned short* __restrict__ Cl,
                 const float* __restrict__ csq,
                 unsigned long long* __restrict__ packed) {
    extern __shared__ unsigned short smem[];   // 2 * LDSBUF elements (128 KB)

    int b  = blockIdx.x;
    int x  = b & 7;
    int m8 = b >> 3;
    int rowtile = x * 32 + (m8 >> 2);
    int coltile = m8 & 3;
    int n0 = rowtile * 256;
    int k0 = coltile * 256;

    int tid  = threadIdx.x;
    int w    = tid >> 6;
    int lane = tid & 63;
    int wr   = w >> 2, wc = w & 3;
    int rbase = wr * 128, cbase = wc * 64;
    int lrow = lane & 15;
    int lk   = lane >> 4;
    int sg   = lk ^ ((lrow >> 1) & 3);

    int srow = tid >> 2;
    int sgrp = tid & 3;
    int r1   = (srow < 64) ? srow : srow + 64;
    int ggA  = sgrp ^ ((r1 >> 1) & 3);
    int gB   = sgrp ^ ((srow >> 1) & 3);
    size_t oA1 = (size_t)(n0 + r1) * DIM + ggA * 8;
    size_t oA2 = oA1 + (size_t)64 * DIM;
    size_t oB0 = (size_t)(k0 + srow) * DIM + gB * 8;
    size_t oB1 = oB0 + (size_t)128 * DIM;
    int rowA1_0 = (w < 4) ? w * 16 : w * 16 + 64;
    int dA1  = rowA1_0 * 32;
    int dA2  = dA1 + 2048;
    int dB0  = 16384 + w * 512;
    int dB1  = dB0 + 4096;
    int dBl0 = dB0 + 8192;
    int dBl1 = dB1 + 8192;

    f32x4 acc[8][4];
    #pragma unroll
    for (int i = 0; i < 8; i++)
        #pragma unroll
        for (int j = 0; j < 4; j++)
            acc[i][j] = (f32x4){0.f, 0.f, 0.f, 0.f};

    bf16x8 bh[4], bl[4];

    auto issue_tile = [&](int t) {
        unsigned short* bufn = smem + (t & 1) * LDSBUF;
        size_t d = (size_t)t * 32;
        gload16(Xh + oA1 + d, bufn + dA1);
        gload16(Xl + oA1 + d, bufn + 8192 + dA1);
        gload16(Ch + oB0 + d, bufn + dB0);
        gload16(Ch + oB1 + d, bufn + dB1);
        gload16(Cl + oB0 + d, bufn + dBl0);
        gload16(Cl + oB1 + d, bufn + dBl1);
        gload16(Xh + oA2 + d, bufn + dA2);
        gload16(Xl + oA2 + d, bufn + 8192 + dA2);
    };

    auto mfma_half = [&](int mb, const bf16x8* ah, const bf16x8* al) {
        __builtin_amdgcn_s_setprio(1);
        #pragma unroll
        for (int mm = 0; mm < 4; mm++)
            #pragma unroll
            for (int n = 0; n < 4; n++)
                acc[mb + mm][n] = __builtin_amdgcn_mfma_f32_16x16x32_bf16(ah[mm], bh[n], acc[mb + mm][n], 0, 0, 0);
        #pragma unroll
        for (int mm = 0; mm < 4; mm++)
            #pragma unroll
            for (int n = 0; n < 4; n++)
                acc[mb + mm][n] = __builtin_amdgcn_mfma_f32_16x16x32_bf16(ah[mm], bl[n], acc[mb + mm][n], 0, 0, 0);
        #pragma unroll
        for (int mm = 0; mm < 4; mm++)
            #pragma unroll
            for (int n = 0; n < 4; n++)
                acc[mb + mm][n] = __builtin_amdgcn_mfma_f32_16x16x32_bf16(al[mm], bh[n], acc[mb + mm][n], 0, 0, 0);
        __builtin_amdgcn_s_setprio(0);
    };

    issue_tile(0);

    for (int t = 0; t < NT; ++t) {
        asm volatile("s_waitcnt vmcnt(0)" ::: "memory");
        __builtin_amdgcn_s_barrier();
        asm volatile("" ::: "memory");

        const unsigned short* buf = smem + (t & 1) * LDSBUF;
        const unsigned short* pA = buf + (rbase + lrow) * 32 + sg * 8;
        const unsigned short* pB = buf + 16384 + (cbase + lrow) * 32 + sg * 8;

        #pragma unroll
        for (int n = 0; n < 4; n++) {
            bh[n] = *(const bf16x8*)(pB + n * 512);
            bl[n] = *(const bf16x8*)(pB + 8192 + n * 512);
        }
        bf16x8 ah[4], al[4];
        #pragma unroll
        for (int mm = 0; mm < 4; mm++) {
            ah[mm] = *(const bf16x8*)(pA + mm * 512);
            al[mm] = *(const bf16x8*)(pA + 8192 + mm * 512);
        }
        if (t + 1 < NT) issue_tile(t + 1);

        mfma_half(0, ah, al);

        bf16x8 ah2[4], al2[4];
        #pragma unroll
        for (int mm = 0; mm < 4; mm++) {
            ah2[mm] = *(const bf16x8*)(pA + (4 + mm) * 512);
            al2[mm] = *(const bf16x8*)(pA + 8192 + (4 + mm) * 512);
        }
        mfma_half(4, ah2, al2);
    }

    float cs[4];
    #pragma unroll
    for (int n = 0; n < 4; n++) cs[n] = csq[k0 + cbase + n * 16 + lrow];

    #pragma unroll
    for (int m = 0; m < 8; m++) {
        #pragma unroll
        for (int r = 0; r < 4; r++) {
            unsigned long long best = ~0ull;
            #pragma unroll
            for (int n = 0; n < 4; n++) {
                float s = cs[n] - 2.0f * acc[m][n][r];
                unsigned kb  = __float_as_uint(s);
                unsigned key = kb ^ (unsigned)(((int)kb >> 31) | 0x80000000);
                unsigned col = (unsigned)(k0 + cbase + n * 16 + lrow);
                unsigned long long pk = (((unsigned long long)key) << 32) | col;
                best = pk < best ? pk : best;
            }
            #pragma unroll
            for (int mask = 1; mask <= 8; mask <<= 1) {
                unsigned hi = __shfl_xor((unsigned)(best >> 32), mask, 64);
                unsigned lo = __shfl_xor((unsigned)(best & 0xFFFFFFFFu), mask, 64);
                unsigned long long other = (((unsigned long long)hi) << 32) | lo;
                best = other < best ? other : best;
            }
            if (lrow == 0) {
                int grow = n0 + rbase + m * 16 + lk * 4 + r;
                atomicMin(&packed[grow], best);
            }
        }
    }
}

__global__ void map_kernel(const unsigned long long* __restrict__ packed,
                           const int* __restrict__ classes,
                           int* __restrict__ out) {
    int n = blockIdx.x * 256 + threadIdx.x;
    if (n < N_ROWS) {
        unsigned col = (unsigned)(packed[n] & 0xFFFFFFFFull);
        out[n] = classes[col];
    }
}

extern "C" void kernel_launch(void* const* d_in, const int* in_sizes, int n_in,
                              void* d_out, int out_size, void* d_ws, size_t ws_size,
                              hipStream_t stream) {
    const float* X       = (const float*)d_in[0];
    const float* C       = (const float*)d_in[1];
    const int*   classes = (const int*)d_in[2];
    int*         out     = (int*)d_out;
    char* ws = (char*)d_ws;

    // ---- fast path layout: csq | Ch | scores(fp16) ----
    {
        size_t off = 0;
        float* csq = (float*)(ws + off);                  off += 4096;
        unsigned short* Ch = (unsigned short*)(ws + off); off += (size_t)K_CB * DIM * 2;
        _Float16* scores = (_Float16*)(ws + off);         off += (size_t)N_ROWS * K_CB * 2;
        if (ws_size >= off) {
            csq_kernel<<<K_CB / 4, 256, 0, stream>>>(C, csq);
            split_hi<<<512, 256, 0, stream>>>(C, Ch, K_CB * DIM / 4);
            hipFuncSetAttribute((const void*)gemm_scores,
                                hipFuncAttributeMaxDynamicSharedMemorySize,
                                2 * LDSBUF_F * (int)sizeof(unsigned short));
            gemm_scores<<<(N_ROWS / 256) * (K_CB / 256), 512,
                          2 * LDSBUF_F * sizeof(unsigned short), stream>>>(
                X, Ch, csq, scores);
            phase2_kernel<<<N_ROWS / 4, 256, 0, stream>>>(X, C, csq, scores, classes, out);
            return;
        }
    }

    // ---- fallback: round-9 3-pass path ----
    size_t off = 0;
    unsigned long long* packed = (unsigned long long*)(ws + off); off += (size_t)N_ROWS * 8;
    float* csq = (float*)(ws + off);                              off += (size_t)K_CB * 4;
    unsigned short* Xh = (unsigned short*)(ws + off);             off += (size_t)N_ROWS * DIM * 2;
    unsigned short* Xl = (unsigned short*)(ws + off);             off += (size_t)N_ROWS * DIM * 2;
    unsigned short* Ch = (unsigned short*)(ws + off);             off += (size_t)K_CB * DIM * 2;
    unsigned short* Cl = (unsigned short*)(ws + off);             off += (size_t)K_CB * DIM * 2;

    init_kernel<<<N_ROWS / 256, 256, 0, stream>>>(packed);
    csq_kernel<<<K_CB / 4, 256, 0, stream>>>(C, csq);
    split_kernel<<<2048, 256, 0, stream>>>(X, Xh, Xl, N_ROWS * DIM / 4);
    split_kernel<<<512, 256, 0, stream>>>(C, Ch, Cl, K_CB * DIM / 4);
    hipFuncSetAttribute((const void*)gemm_argmin,
                        hipFuncAttributeMaxDynamicSharedMemorySize,
                        2 * LDSBUF * (int)sizeof(unsigned short));
    gemm_argmin<<<(N_ROWS / 256) * (K_CB / 256), 512,
                  2 * LDSBUF * sizeof(unsigned short), stream>>>(
        Xh, Xl, Ch, Cl, csq, packed);
    map_kernel<<<N_ROWS / 256, 256, 0, stream>>>(packed, classes, out);
}